// Round 2
// baseline (1821.337 us; speedup 1.0000x reference)
//
#include <hip/hip_runtime.h>
#include <hip/hip_bf16.h>
#include <math.h>

#define B_    2
#define S_    2048
#define H_    4096
#define NH_   32
#define HD_   128
#define MTOK_ (B_ * S_)     // 4096 tokens
#define QKVN_ (3 * H_)      // 12288

using bf16_t = __hip_bfloat16;
typedef __bf16 bf16x8 __attribute__((ext_vector_type(8)));
typedef unsigned short u16x8 __attribute__((ext_vector_type(8)));
typedef float f32x4 __attribute__((ext_vector_type(4)));

// async global->LDS, 16B per lane; LDS base must be wave-uniform
// (HW writes lane i at base + i*16B).
#define ASYNC_COPY16(g, l)                                                     \
  __builtin_amdgcn_global_load_lds(                                            \
      (__attribute__((address_space(1))) void*)(g),                            \
      (__attribute__((address_space(3))) void*)(l), 16, 0, 0)

static __device__ __forceinline__ f32x4 mfma16x16(bf16x8 a, bf16x8 b, f32x4 c) {
  return __builtin_amdgcn_mfma_f32_16x16x32_bf16(a, b, c, 0, 0, 0);
}

static __device__ __forceinline__ float bits_to_f(unsigned short v) {
  union { unsigned int u; float f; } cv;
  cv.u = ((unsigned int)v) << 16;
  return cv.f;
}

// ---------------------------------------------------------------------------
// dtype probe: if the float inputs are fp32, random mantissa halves decode to
// huge bf16 values; if genuine bf16 (|x|<~0.2 here), all 64K u16s stay small.
// ---------------------------------------------------------------------------
__global__ void bh_detect(const unsigned short* __restrict__ p,
                          int* __restrict__ flag) {
  __shared__ float red[4];
  float m = 0.f;
  const int tid = threadIdx.x;
  for (int i = tid; i < 65536; i += 256) {
    const float f = fabsf(bits_to_f(p[i]));
    m = fmaxf(m, f);  // fmaxf(m, NaN) == m
  }
  for (int off = 1; off < 64; off <<= 1) m = fmaxf(m, __shfl_xor(m, off, 64));
  if ((tid & 63) == 0) red[tid >> 6] = m;
  __syncthreads();
  if (tid == 0) {
    const float mm = fmaxf(fmaxf(red[0], red[1]), fmaxf(red[2], red[3]));
    *flag = (mm > 1.0f) ? 1 : 0;  // 1 => inputs/outputs are fp32
  }
}

// fp32 staging: read 8 floats, convert, one ds_write_b128 (same LDS layout
// the async path produces).
static __device__ __forceinline__ void stage32(const float* __restrict__ g,
                                               bf16_t* __restrict__ l) {
  const f32x4 f0 = *reinterpret_cast<const f32x4*>(g);
  const f32x4 f1 = *reinterpret_cast<const f32x4*>(g + 4);
  bf16x8 o;
  o[0] = (__bf16)f0[0]; o[1] = (__bf16)f0[1];
  o[2] = (__bf16)f0[2]; o[3] = (__bf16)f0[3];
  o[4] = (__bf16)f1[0]; o[5] = (__bf16)f1[1];
  o[6] = (__bf16)f1[2]; o[7] = (__bf16)f1[3];
  *reinterpret_cast<bf16x8*>(l) = o;
}

// ---------------------------------------------------------------------------
// NT GEMM: C[m][n] = sum_k A[m][k]*Bw[n][k]. 128x128 tile, BK=32, 4 waves,
// 4x4 acc of 16x16x32 bf16 MFMA. AMODE/BMODE: 0 = operand always bf16,
// 1 = dtype per runtime flag. CMODE: 0 = store bf16, 1 = store per flag.
// ---------------------------------------------------------------------------
template <int AMODE, int BMODE, int CMODE>
__global__ __launch_bounds__(256, 2)
void bh_gemm(const void* __restrict__ Ap, int lda,
             const void* __restrict__ Bp, int ldb,
             void* __restrict__ Cp, int ldc, int N, int K,
             const int* __restrict__ flag) {
  __shared__ bf16_t As[128 * 32];
  __shared__ bf16_t Bs[128 * 32];
  const int isf = *flag;
  const bool a_f32 = AMODE && isf;
  const bool b_f32 = BMODE && isf;

  const int tid = threadIdx.x, wave = tid >> 6, lane = tid & 63;
  const int lq = lane >> 4, lc = lane & 15;
  const int m0 = blockIdx.y * 128, n0 = blockIdx.x * 128;
  const int wm = (wave >> 1) * 64, wn = (wave & 1) * 64;

  f32x4 acc[4][4] = {};

  const int srow  = wave * 16 + (lane >> 2);  // staging row (lane i -> i/4)
  const int skoff = (lane & 3) * 8;           // k-chunk of 8 elements

  const bf16_t* a16 = (const bf16_t*)Ap;
  const float*  a32 = (const float*)Ap;
  const bf16_t* b16 = (const bf16_t*)Bp;
  const float*  b32 = (const float*)Bp;

  bf16_t* lA0u = As + wave * 512;          // wave-uniform async bases
  bf16_t* lA1u = As + 2048 + wave * 512;
  bf16_t* lB0u = Bs + wave * 512;
  bf16_t* lB1u = Bs + 2048 + wave * 512;
  bf16_t* lA0p = lA0u + lane * 8;          // per-lane manual bases
  bf16_t* lA1p = lA1u + lane * 8;
  bf16_t* lB0p = lB0u + lane * 8;
  bf16_t* lB1p = lB1u + lane * 8;

  const int aoff = (wm + lc) * 32 + lq * 8;
  const int boff = (wn + lc) * 32 + lq * 8;

  for (int k = 0; k < K; k += 32) {
    if (a_f32) {
      stage32(a32 + (long)(m0 + srow) * lda + skoff + k, lA0p);
      stage32(a32 + (long)(m0 + srow + 64) * lda + skoff + k, lA1p);
    } else {
      ASYNC_COPY16(a16 + (long)(m0 + srow) * lda + skoff + k, lA0u);
      ASYNC_COPY16(a16 + (long)(m0 + srow + 64) * lda + skoff + k, lA1u);
    }
    if (b_f32) {
      stage32(b32 + (long)(n0 + srow) * ldb + skoff + k, lB0p);
      stage32(b32 + (long)(n0 + srow + 64) * ldb + skoff + k, lB1p);
    } else {
      ASYNC_COPY16(b16 + (long)(n0 + srow) * ldb + skoff + k, lB0u);
      ASYNC_COPY16(b16 + (long)(n0 + srow + 64) * ldb + skoff + k, lB1u);
    }
    __syncthreads();
    bf16x8 af[4], bfr[4];
#pragma unroll
    for (int i = 0; i < 4; ++i) {
      af[i]  = *reinterpret_cast<const bf16x8*>(&As[aoff + i * 512]);
      bfr[i] = *reinterpret_cast<const bf16x8*>(&Bs[boff + i * 512]);
    }
#pragma unroll
    for (int mi = 0; mi < 4; ++mi)
#pragma unroll
      for (int ni = 0; ni < 4; ++ni)
        acc[mi][ni] = mfma16x16(af[mi], bfr[ni], acc[mi][ni]);
    __syncthreads();
  }

  const bool c_f32 = CMODE && isf;
#pragma unroll
  for (int mi = 0; mi < 4; ++mi)
#pragma unroll
    for (int ni = 0; ni < 4; ++ni)
#pragma unroll
      for (int i = 0; i < 4; ++i) {
        const long row = m0 + wm + mi * 16 + lq * 4 + i;
        const long col = n0 + wn + ni * 16 + lc;
        const float v = acc[mi][ni][i];
        if (c_f32)
          ((float*)Cp)[row * ldc + col] = v;
        else
          ((bf16_t*)Cp)[row * ldc + col] = __float2bfloat16(v);
      }
}

// ---------------------------------------------------------------------------
// RoPE (neox half-split) in-place on Q and K regions of qkv (bf16).
// ---------------------------------------------------------------------------
__global__ void bh_rope(bf16_t* __restrict__ qkv, const int* __restrict__ pos) {
  const int idx = blockIdx.x * 256 + threadIdx.x;
  const int d = idx & 63;
  const int h = (idx >> 6) & (NH_ - 1);
  const int m = idx >> 11;
  if (m >= MTOK_) return;
  const float p = (float)pos[m];
  const float inv_freq = 1.0f / powf(10000.0f, (float)d * (1.0f / 64.0f));
  float sn, cs;
  sincosf(p * inv_freq, &sn, &cs);
  bf16_t* q  = qkv + (long)m * QKVN_ + h * HD_;
  bf16_t* kk = q + H_;
  const float q1 = __bfloat162float(q[d]);
  const float q2 = __bfloat162float(q[d + 64]);
  q[d]      = __float2bfloat16(q1 * cs - q2 * sn);
  q[d + 64] = __float2bfloat16(q2 * cs + q1 * sn);
  const float k1 = __bfloat162float(kk[d]);
  const float k2 = __bfloat162float(kk[d + 64]);
  kk[d]      = __float2bfloat16(k1 * cs - k2 * sn);
  kk[d + 64] = __float2bfloat16(k2 * cs + k1 * sn);
}

// ---------------------------------------------------------------------------
// V transpose: qkv V region [token][h*128+d] -> vt[b][h][d][token]
// ---------------------------------------------------------------------------
__global__ void bh_transpose_v(const bf16_t* __restrict__ qkv,
                               bf16_t* __restrict__ vt) {
  __shared__ unsigned short tile[128][65];
  const int t0 = blockIdx.x * 64;
  const int h  = blockIdx.y;
  const int b  = blockIdx.z;
  const int tid = threadIdx.x;
#pragma unroll
  for (int pass = 0; pass < 4; ++pass) {
    const int row = (tid >> 4) + pass * 16;
    const int dc  = (tid & 15) * 8;
    const u16x8 v = *reinterpret_cast<const u16x8*>(
        qkv + (long)(b * S_ + t0 + row) * QKVN_ + 2 * H_ + h * HD_ + dc);
#pragma unroll
    for (int j = 0; j < 8; ++j) tile[dc + j][row] = v[j];
  }
  __syncthreads();
#pragma unroll
  for (int pass = 0; pass < 4; ++pass) {
    const int d  = (tid >> 3) + pass * 32;
    const int tc = (tid & 7) * 8;
    u16x8 o;
#pragma unroll
    for (int j = 0; j < 8; ++j) o[j] = tile[d][tc + j];
    *reinterpret_cast<u16x8*>(
        vt + ((long)(b * NH_ + h) * HD_ + d) * S_ + t0 + tc) = o;
  }
}

// ---------------------------------------------------------------------------
// Causal flash attention. Output written into the Q region of qkv (each block
// overwrites exactly the Q rows/cols only it reads, after loading Q to regs).
// ---------------------------------------------------------------------------
__global__ __launch_bounds__(256)
void bh_flash(bf16_t* __restrict__ qkv, const bf16_t* __restrict__ vt) {
  __shared__ bf16_t Ks[64 * 128];   // [token][dim]
  __shared__ bf16_t Vs[128 * 64];   // [dim][token]
  __shared__ bf16_t Ps[128 * 64];   // [qrow][token]
  const int qt = blockIdx.x, h = blockIdx.y, b = blockIdx.z;
  const int tid = threadIdx.x, wave = tid >> 6, lane = tid & 63;
  const int lq = lane >> 4, lc = lane & 15;
  const int wrow = wave * 32;
  const float scale = 0.088388347648318447f;  // 1/sqrt(128)

  bf16x8 qf[2][4];
#pragma unroll
  for (int mt = 0; mt < 2; ++mt) {
    const bf16_t* qp =
        qkv + (long)(b * S_ + qt * 128 + wrow + mt * 16 + lc) * QKVN_ +
        h * HD_ + lq * 8;
#pragma unroll
    for (int ks = 0; ks < 4; ++ks)
      qf[mt][ks] = *reinterpret_cast<const bf16x8*>(qp + ks * 32);
  }

  f32x4 o_acc[2][8] = {};
  float m_st[2][4], l_st[2][4];
#pragma unroll
  for (int mt = 0; mt < 2; ++mt)
#pragma unroll
    for (int i = 0; i < 4; ++i) { m_st[mt][i] = -1e30f; l_st[mt][i] = 0.f; }

  const int ktiles = 2 * qt + 2;
  for (int kt = 0; kt < ktiles; ++kt) {
    const int t0 = kt * 64;
#pragma unroll
    for (int j = 0; j < 4; ++j) {
      const int p = wave * 4 + j;
      ASYNC_COPY16(qkv + (long)(b * S_ + t0 + p * 4 + (lane >> 4)) * QKVN_ +
                       H_ + h * HD_ + (lane & 15) * 8,
                   Ks + p * 512);
      ASYNC_COPY16(vt + ((long)(b * NH_ + h) * HD_ + p * 8 + (lane >> 3)) * S_ +
                       t0 + (lane & 7) * 8,
                   Vs + p * 512);
    }
    __syncthreads();

    f32x4 sa[2][4] = {};
#pragma unroll
    for (int ks = 0; ks < 4; ++ks) {
      bf16x8 bb[4];
#pragma unroll
      for (int nt = 0; nt < 4; ++nt)
        bb[nt] = *reinterpret_cast<const bf16x8*>(
            &Ks[(nt * 16 + lc) * 128 + ks * 32 + lq * 8]);
#pragma unroll
      for (int mt = 0; mt < 2; ++mt)
#pragma unroll
        for (int nt = 0; nt < 4; ++nt)
          sa[mt][nt] = mfma16x16(qf[mt][ks], bb[nt], sa[mt][nt]);
    }

#pragma unroll
    for (int mt = 0; mt < 2; ++mt) {
#pragma unroll
      for (int i = 0; i < 4; ++i) {
        const int qg = qt * 128 + wrow + mt * 16 + lq * 4 + i;
        float sv[4];
        float mloc = -1e30f;
#pragma unroll
        for (int nt = 0; nt < 4; ++nt) {
          float v = sa[mt][nt][i] * scale;
          if (t0 + nt * 16 + lc > qg) v = -1e30f;
          sv[nt] = v;
          mloc = fmaxf(mloc, v);
        }
#pragma unroll
        for (int off = 1; off < 16; off <<= 1)
          mloc = fmaxf(mloc, __shfl_xor(mloc, off, 64));
        const float mnew = fmaxf(m_st[mt][i], mloc);
        const float alpha = __expf(m_st[mt][i] - mnew);
        float rsum = 0.f;
#pragma unroll
        for (int nt = 0; nt < 4; ++nt) {
          const float pp = __expf(sv[nt] - mnew);
          rsum += pp;
          Ps[(wrow + mt * 16 + lq * 4 + i) * 64 + nt * 16 + lc] =
              __float2bfloat16(pp);
        }
#pragma unroll
        for (int off = 1; off < 16; off <<= 1)
          rsum += __shfl_xor(rsum, off, 64);
        l_st[mt][i] = l_st[mt][i] * alpha + rsum;
        m_st[mt][i] = mnew;
#pragma unroll
        for (int nt = 0; nt < 8; ++nt) o_acc[mt][nt][i] *= alpha;
      }
    }
    __syncthreads();

#pragma unroll
    for (int ks = 0; ks < 2; ++ks) {
      bf16x8 pa[2];
#pragma unroll
      for (int mt = 0; mt < 2; ++mt)
        pa[mt] = *reinterpret_cast<const bf16x8*>(
            &Ps[(wrow + mt * 16 + lc) * 64 + ks * 32 + lq * 8]);
#pragma unroll
      for (int nt = 0; nt < 8; ++nt) {
        const bf16x8 vb = *reinterpret_cast<const bf16x8*>(
            &Vs[(nt * 16 + lc) * 64 + ks * 32 + lq * 8]);
#pragma unroll
        for (int mt = 0; mt < 2; ++mt)
          o_acc[mt][nt] = mfma16x16(pa[mt], vb, o_acc[mt][nt]);
      }
    }
    __syncthreads();
  }

  // write attention output into the Q region of qkv
#pragma unroll
  for (int mt = 0; mt < 2; ++mt)
#pragma unroll
    for (int i = 0; i < 4; ++i) {
      const float inv_l = 1.0f / l_st[mt][i];
      bf16_t* op =
          qkv + (long)(b * S_ + qt * 128 + wrow + mt * 16 + lq * 4 + i) * QKVN_ +
          h * HD_ + lc;
#pragma unroll
      for (int nt = 0; nt < 8; ++nt)
        op[nt * 16] = __float2bfloat16(o_acc[mt][nt][i] * inv_l);
    }
}

// ---------------------------------------------------------------------------
extern "C" void kernel_launch(void* const* d_in, const int* in_sizes, int n_in,
                              void* d_out, int out_size, void* d_ws,
                              size_t ws_size, hipStream_t stream) {
  const int* pos = (const int*)d_in[3];

  char* ws = (char*)d_ws;
  bf16_t* qkv  = (bf16_t*)ws;                                   // 100.66 MB
  int*    flag = (int*)(ws + (size_t)MTOK_ * QKVN_ * 2);
  bf16_t* vt   = (bf16_t*)d_out;  // scratch before final out is written

  bh_detect<<<dim3(1), dim3(256), 0, stream>>>(
      (const unsigned short*)d_in[1], flag);
  bh_gemm<1, 1, 0><<<dim3(QKVN_ / 128, MTOK_ / 128), dim3(256), 0, stream>>>(
      d_in[0], H_, d_in[1], H_, qkv, QKVN_, QKVN_, H_, flag);
  bh_rope<<<dim3((MTOK_ * NH_ * 64) / 256), dim3(256), 0, stream>>>(qkv, pos);
  bh_transpose_v<<<dim3(S_ / 64, NH_, B_), dim3(256), 0, stream>>>(qkv, vt);
  bh_flash<<<dim3(S_ / 128, NH_, B_), dim3(256), 0, stream>>>(qkv, vt);
  bh_gemm<0, 1, 1><<<dim3(H_ / 128, MTOK_ / 128), dim3(256), 0, stream>>>(
      qkv, QKVN_, d_in[2], H_, d_out, H_, H_, H_, flag);
}